// Round 4
// baseline (4916.582 us; speedup 1.0000x reference)
//
#include <hip/hip_runtime.h>
#include <stdint.h>

namespace {

constexpr int B_ROWS = 131072;

typedef __attribute__((ext_vector_type(8))) short bf16x8;
typedef __attribute__((ext_vector_type(4))) float f32x4;

__device__ __forceinline__ unsigned short f2bf(float f) {
  unsigned u = __builtin_bit_cast(unsigned, f);
  u += 0x7fffu + ((u >> 16) & 1u);
  return (unsigned short)(u >> 16);
}
__device__ __forceinline__ float bf2f(unsigned short h) {
  unsigned u = ((unsigned)h) << 16;
  return __builtin_bit_cast(float, u);
}
__device__ __forceinline__ float sigm(float v) { return 1.0f / (1.0f + __expf(-v)); }

// ---------- weight packing ----------

__global__ void pack_t_k(const float* __restrict__ W, unsigned short* __restrict__ Wt) {
  int idx = blockIdx.x * 256 + threadIdx.x;  // 512*512
  int n = idx >> 9, k = idx & 511;
  Wt[idx] = f2bf(W[(k << 9) + n]);
}

__global__ void pack_zgr_k(const float* __restrict__ dgmW, unsigned short* __restrict__ Wt) {
  long idx = (long)blockIdx.x * 256 + threadIdx.x;  // 3*1536*1024
  int l = (int)(idx / (1536 * 1024));
  int rest = (int)(idx - (long)l * (1536 * 1024));
  int n = rest >> 10, k = rest & 1023;
  int g = n >> 9, nn = n & 511;
  const int xi0[3] = {0, 3, 6};
  const int xi1[3] = {2, 4, 8};
  const int si[3] = {1, 5, 7};
  float v;
  if (k < 512)
    v = dgmW[(((long)(l * 12 + xi0[g]) << 9) + k) * 512 + nn] +
        dgmW[(((long)(l * 12 + xi1[g]) << 9) + k) * 512 + nn];
  else
    v = dgmW[(((long)(l * 12 + si[g]) << 9) + (k - 512)) * 512 + nn];
  Wt[idx] = f2bf(v);
}

__global__ void pack_h_k(const float* __restrict__ dgmW, unsigned short* __restrict__ Wt) {
  long idx = (long)blockIdx.x * 256 + threadIdx.x;  // 3*512*1024
  int l = (int)(idx / (512 * 1024));
  int rest = (int)(idx - (long)l * (512 * 1024));
  int n = rest >> 10, k = rest & 1023;
  float v;
  if (k < 512)
    v = dgmW[(((long)(l * 12 + 9) << 9) + k) * 512 + n] +
        dgmW[(((long)(l * 12 + 11) << 9) + k) * 512 + n];
  else
    v = dgmW[(((long)(l * 12 + 10) << 9) + (k - 512)) * 512 + n];
  Wt[idx] = f2bf(v);
}

__global__ void pack_bias_k(const float* __restrict__ dgmb, float* __restrict__ bzgr,
                            float* __restrict__ bh) {
  int idx = blockIdx.x * 256 + threadIdx.x;  // 3*2048
  if (idx >= 3 * 2048) return;
  int l = idx >> 11, n = idx & 2047;
  const float* bl = dgmb + l * 12 * 512;
  if (n < 1536) {
    int g = n >> 9, nn = n & 511;
    bzgr[l * 1536 + n] =
        bl[(g * 3 + 0) * 512 + nn] + bl[(g * 3 + 1) * 512 + nn] + bl[(g * 3 + 2) * 512 + nn];
  } else {
    int nn = n - 1536;
    bh[l * 512 + nn] = bl[9 * 512 + nn] + bl[10 * 512 + nn] + bl[11 * 512 + nn];
  }
}

// ---------- front input layer ----------
__global__ void front0_k(const float* __restrict__ X, const float* __restrict__ t,
                         const float* __restrict__ Win, const float* __restrict__ bin,
                         unsigned short* __restrict__ x0, long row0) {
  long idx = (long)blockIdx.x * 256 + threadIdx.x;  // rows*512
  long r = idx >> 9;
  int c = (int)(idx & 511);
  long gr = row0 + r;
  float a = X[gr * 2] * Win[c] + X[gr * 2 + 1] * Win[512 + c] + t[gr] * Win[1024 + c] + bin[c];
  x0[idx] = f2bf(tanhf(a));
}

// ---------- output head ----------
__global__ void head_k(const unsigned short* __restrict__ S, const float* __restrict__ Wout,
                       const float* __restrict__ bout, float* __restrict__ out, long row0) {
  const int lane = threadIdx.x & 63, wid = threadIdx.x >> 6;
  const long r = (long)blockIdx.x * 4 + wid;
  bf16x8 sv = *(const bf16x8*)&S[r * 512 + lane * 8];
  float sum = 0.f;
#pragma unroll
  for (int i = 0; i < 8; ++i) sum += bf2f((unsigned short)sv[i]) * Wout[lane * 8 + i];
#pragma unroll
  for (int off = 32; off > 0; off >>= 1) sum += __shfl_down(sum, off);
  if (lane == 0) out[row0 + r] = sum + bout[0];
}

// ---------- barrier-free GEMM: B-resident-in-LDS, A direct-from-global ----------
// C[row][col] = act( sum_k A[row][k]*Wt[col][k] + bias[col] )
// Block: 64 cols x K (KHALVES*512) of Wt in LDS (loaded once, 1 barrier),
// 512 rows of A streamed straight from global into MFMA A-fragments.
// 8 waves, wave w owns rows [w*64, w*64+64): acc[4][4] f32x4 (64 VGPR).
// Main loop has NO barriers / NO waitcnt asm: per k-slice 4 global A-loads +
// 4 swizzled ds_reads + 16 independent MFMAs; 2 waves/SIMD antiphase hides
// latency (m114). LDS swizzle: phys_k8 = k8 ^ (col&7) on write and read;
// read pattern is 2-way (free, m136), write is conflict-free.
template <int EPI, int KHALVES>
__global__ __launch_bounds__(512, 2) void gemmN64_k(
    const unsigned short* __restrict__ a0, const unsigned short* __restrict__ a1,
    const unsigned short* __restrict__ wt, const float* __restrict__ bias,
    unsigned short* __restrict__ o0, unsigned short* __restrict__ o1,
    unsigned short* __restrict__ o2, const unsigned short* __restrict__ e0,
    const unsigned short* __restrict__ e1) {
  constexpr int K = KHALVES * 512;
  constexpr int K8 = K / 8;  // 16B units per col
  extern __shared__ unsigned short lds[];
  const int tid = threadIdx.x;

  // T1: bijective XCD swizzle (m204); col fastest -> the col-blocks sharing
  // one 512-row A-panel run on one XCD (panel 1MB << 4MB L2).
  const int gx = gridDim.x;
  const int nwg = gx * (int)gridDim.y;
  const int orig = (int)blockIdx.y * gx + (int)blockIdx.x;
  const int q = nwg >> 3, rr = nwg & 7;
  const int xcd = orig & 7, lo = orig >> 3;
  const int wg = ((xcd < rr) ? xcd * (q + 1) : rr * (q + 1) + (xcd - rr) * q) + lo;
  const long brow = (long)(wg / gx) * 512;
  const int bcol = (wg % gx) * 64;

  // stage B [64][K] -> swizzled LDS (once)
#pragma unroll
  for (int i = 0; i < (64 * K8) / 512; ++i) {
    const int c = tid + (i << 9);
    const int col = c / K8, k8 = c % K8;
    bf16x8 v = *(const bf16x8*)(wt + (size_t)(bcol + col) * K + k8 * 8);
    *(bf16x8*)(lds + col * K + ((k8 ^ (col & 7)) << 3)) = v;
  }
  __syncthreads();

  const int lane = tid & 63, w = tid >> 6;
  const int lr = lane & 15, kk = lane >> 4;
  const long rbase = brow + w * 64 + lr;
  f32x4 acc[4][4] = {};

#pragma unroll
  for (int kh = 0; kh < KHALVES; ++kh) {
    const unsigned short* __restrict__ asrc = kh ? a1 : a0;
#pragma unroll 4
    for (int ks = 0; ks < 16; ++ks) {
      const int kw = ks * 32 + kk * 8;               // k-offset within this 512-half
      const int k8g = kh * 64 + ks * 4 + kk;         // global 16B-unit index
      const int bko = ((k8g ^ (lr & 7)) << 3);       // swizzled k-offset (shorts)
      bf16x8 af0 = *(const bf16x8*)(asrc + (rbase + 0) * 512 + kw);
      bf16x8 af1 = *(const bf16x8*)(asrc + (rbase + 16) * 512 + kw);
      bf16x8 af2 = *(const bf16x8*)(asrc + (rbase + 32) * 512 + kw);
      bf16x8 af3 = *(const bf16x8*)(asrc + (rbase + 48) * 512 + kw);
      bf16x8 bf0 = *(const bf16x8*)(lds + (0 * 16 + lr) * K + bko);
      bf16x8 bf1 = *(const bf16x8*)(lds + (1 * 16 + lr) * K + bko);
      bf16x8 bf2 = *(const bf16x8*)(lds + (2 * 16 + lr) * K + bko);
      bf16x8 bf3 = *(const bf16x8*)(lds + (3 * 16 + lr) * K + bko);
      acc[0][0] = __builtin_amdgcn_mfma_f32_16x16x32_bf16(af0, bf0, acc[0][0], 0, 0, 0);
      acc[0][1] = __builtin_amdgcn_mfma_f32_16x16x32_bf16(af0, bf1, acc[0][1], 0, 0, 0);
      acc[0][2] = __builtin_amdgcn_mfma_f32_16x16x32_bf16(af0, bf2, acc[0][2], 0, 0, 0);
      acc[0][3] = __builtin_amdgcn_mfma_f32_16x16x32_bf16(af0, bf3, acc[0][3], 0, 0, 0);
      acc[1][0] = __builtin_amdgcn_mfma_f32_16x16x32_bf16(af1, bf0, acc[1][0], 0, 0, 0);
      acc[1][1] = __builtin_amdgcn_mfma_f32_16x16x32_bf16(af1, bf1, acc[1][1], 0, 0, 0);
      acc[1][2] = __builtin_amdgcn_mfma_f32_16x16x32_bf16(af1, bf2, acc[1][2], 0, 0, 0);
      acc[1][3] = __builtin_amdgcn_mfma_f32_16x16x32_bf16(af1, bf3, acc[1][3], 0, 0, 0);
      acc[2][0] = __builtin_amdgcn_mfma_f32_16x16x32_bf16(af2, bf0, acc[2][0], 0, 0, 0);
      acc[2][1] = __builtin_amdgcn_mfma_f32_16x16x32_bf16(af2, bf1, acc[2][1], 0, 0, 0);
      acc[2][2] = __builtin_amdgcn_mfma_f32_16x16x32_bf16(af2, bf2, acc[2][2], 0, 0, 0);
      acc[2][3] = __builtin_amdgcn_mfma_f32_16x16x32_bf16(af2, bf3, acc[2][3], 0, 0, 0);
      acc[3][0] = __builtin_amdgcn_mfma_f32_16x16x32_bf16(af3, bf0, acc[3][0], 0, 0, 0);
      acc[3][1] = __builtin_amdgcn_mfma_f32_16x16x32_bf16(af3, bf1, acc[3][1], 0, 0, 0);
      acc[3][2] = __builtin_amdgcn_mfma_f32_16x16x32_bf16(af3, bf2, acc[3][2], 0, 0, 0);
      acc[3][3] = __builtin_amdgcn_mfma_f32_16x16x32_bf16(af3, bf3, acc[3][3], 0, 0, 0);
    }
  }

  // epilogue
#pragma unroll
  for (int m = 0; m < 4; ++m) {
#pragma unroll
    for (int n = 0; n < 4; ++n) {
      const int col = bcol + n * 16 + lr;
      const float bs = bias[col];
#pragma unroll
      for (int j = 0; j < 4; ++j) {
        const long row = brow + w * 64 + m * 16 + kk * 4 + j;
        float v = acc[m][n][j] + bs;
        if constexpr (EPI == 0) {
          o0[row * 512 + col] = f2bf(tanhf(v));
        } else if constexpr (EPI == 1) {
          unsigned short b = f2bf(v);
          o0[row * 512 + col] = b;
          o1[row * 512 + col] = b;
        } else if constexpr (EPI == 2) {
          const int g = col >> 9;
          const int nn = col & 511;
          const float sgv = sigm(v);
          if (g == 0) {
            o0[row * 512 + nn] = f2bf(sgv * bf2f(e0[row * 512 + nn]));  // Z*S
          } else if (g == 1) {
            o1[row * 512 + nn] = f2bf(1.0f - sgv);  // 1-G
          } else {
            o2[row * 512 + nn] = f2bf(sgv * bf2f(e0[row * 512 + nn]));  // S*R
          }
        } else {
          const float h = tanhf(v);
          const float omg = bf2f(e0[row * 512 + col]);
          const float zs = bf2f(e1[row * 512 + col]);
          o0[row * 512 + col] = f2bf(omg * h + zs);  // S_new
        }
      }
    }
  }
}

}  // namespace

extern "C" void kernel_launch(void* const* d_in, const int* in_sizes, int n_in,
                              void* d_out, int out_size, void* d_ws, size_t ws_size,
                              hipStream_t stream) {
  const float* X = (const float*)d_in[0];
  const float* t = (const float*)d_in[1];
  const float* W_in = (const float*)d_in[2];
  const float* b_in = (const float*)d_in[3];
  const float* W_h1 = (const float*)d_in[4];
  const float* b_h1 = (const float*)d_in[5];
  const float* W_hd = (const float*)d_in[6];
  const float* b_hd = (const float*)d_in[7];
  const float* dgm_W = (const float*)d_in[8];
  const float* dgm_b = (const float*)d_in[9];
  const float* W_out = (const float*)d_in[10];
  const float* b_out = (const float*)d_in[11];
  float* out = (float*)d_out;
  char* ws = (char*)d_ws;

  // allow big dynamic LDS (host-side, capture-safe)
  (void)hipFuncSetAttribute((const void*)&gemmN64_k<0, 1>,
                            hipFuncAttributeMaxDynamicSharedMemorySize, 65536);
  (void)hipFuncSetAttribute((const void*)&gemmN64_k<1, 1>,
                            hipFuncAttributeMaxDynamicSharedMemorySize, 65536);
  (void)hipFuncSetAttribute((const void*)&gemmN64_k<2, 2>,
                            hipFuncAttributeMaxDynamicSharedMemorySize, 131072);
  (void)hipFuncSetAttribute((const void*)&gemmN64_k<3, 2>,
                            hipFuncAttributeMaxDynamicSharedMemorySize, 131072);

  size_t off = 0;
  auto alloc = [&](size_t bytes) {
    size_t o = off;
    off = (off + bytes + 255) & ~(size_t)255;
    return o;
  };
  size_t o_wth1 = alloc((size_t)512 * 512 * 2);
  size_t o_wthd = alloc((size_t)512 * 512 * 2);
  size_t o_wtzgr = alloc((size_t)3 * 1536 * 1024 * 2);
  size_t o_wth = alloc((size_t)3 * 512 * 1024 * 2);
  size_t o_bzgr = alloc((size_t)3 * 1536 * 4);
  size_t o_bh = alloc((size_t)3 * 512 * 4);
  size_t actoff = off;

  unsigned short* wth1 = (unsigned short*)(ws + o_wth1);
  unsigned short* wthd = (unsigned short*)(ws + o_wthd);
  unsigned short* wtzgr = (unsigned short*)(ws + o_wtzgr);
  unsigned short* wth = (unsigned short*)(ws + o_wth);
  float* bzgr = (float*)(ws + o_bzgr);
  float* bh = (float*)(ws + o_bh);

  // chunk batch so 5 bf16 [R,512] activation buffers fit in remaining ws;
  // R must stay a multiple of 512 (block M-extent)
  size_t avail = ws_size > actoff ? ws_size - actoff : 0;
  int nch = 1;
  while (nch < 256 && (size_t)(B_ROWS / nch) * 512 * 2 * 5 > avail) nch <<= 1;
  const int R = B_ROWS / nch;
  unsigned short* xb = (unsigned short*)(ws + actoff);
  unsigned short* Sb = xb + (size_t)R * 512;
  unsigned short* ZSb = Sb + (size_t)R * 512;
  unsigned short* OGb = ZSb + (size_t)R * 512;
  unsigned short* SRb = OGb + (size_t)R * 512;

  pack_t_k<<<1024, 256, 0, stream>>>(W_h1, wth1);
  pack_t_k<<<1024, 256, 0, stream>>>(W_hd, wthd);
  pack_zgr_k<<<18432, 256, 0, stream>>>(dgm_W, wtzgr);
  pack_h_k<<<6144, 256, 0, stream>>>(dgm_W, wth);
  pack_bias_k<<<24, 256, 0, stream>>>(dgm_b, bzgr, bh);

  for (int c = 0; c < nch; ++c) {
    long row0 = (long)c * R;
    dim3 g8(8, R / 512), g24(24, R / 512);
    // x0 = tanh(inp@W_in + b_in)  -> ZSb (scratch)
    front0_k<<<R * 2, 256, 0, stream>>>(X, t, W_in, b_in, ZSb, row0);
    // x1 = tanh(x0@W_h1 + b_h1)   -> OGb (scratch)
    gemmN64_k<0, 1><<<g8, 512, 65536, stream>>>(ZSb, ZSb, wth1, b_h1, OGb, nullptr, nullptr,
                                                nullptr, nullptr);
    // x = x1@W_hd + b_hd          -> xb and Sb
    gemmN64_k<1, 1><<<g8, 512, 65536, stream>>>(OGb, OGb, wthd, b_hd, xb, Sb, nullptr,
                                                nullptr, nullptr);
    for (int l = 0; l < 3; ++l) {
      // gates: [x|S] @ Wzgr -> Z*S, 1-G, S*R
      gemmN64_k<2, 2><<<g24, 512, 131072, stream>>>(xb, Sb, wtzgr + (size_t)l * 1536 * 1024,
                                                    bzgr + l * 1536, ZSb, OGb, SRb, Sb, nullptr);
      // H + S update: [x|S*R] @ Wh ; S = (1-G)*tanh + Z*S
      gemmN64_k<3, 2><<<g8, 512, 131072, stream>>>(xb, SRb, wth + (size_t)l * 512 * 1024,
                                                   bh + l * 512, Sb, nullptr, nullptr, OGb, ZSb);
    }
    head_k<<<R / 4, 256, 0, stream>>>(Sb, W_out, b_out, out, row0);
  }
}

// Round 5
// 3418.510 us; speedup vs baseline: 1.4382x; 1.4382x over previous
//
#include <hip/hip_runtime.h>
#include <stdint.h>

namespace {

constexpr int B_ROWS = 131072;

typedef __attribute__((ext_vector_type(8))) short bf16x8;
typedef __attribute__((ext_vector_type(4))) float f32x4;

__device__ __forceinline__ unsigned short f2bf(float f) {
  unsigned u = __builtin_bit_cast(unsigned, f);
  u += 0x7fffu + ((u >> 16) & 1u);
  return (unsigned short)(u >> 16);
}
__device__ __forceinline__ float bf2f(unsigned short h) {
  unsigned u = ((unsigned)h) << 16;
  return __builtin_bit_cast(float, u);
}
__device__ __forceinline__ float sigm(float v) { return 1.0f / (1.0f + __expf(-v)); }

// ---------- weight packing ----------

__global__ void pack_t_k(const float* __restrict__ W, unsigned short* __restrict__ Wt) {
  int idx = blockIdx.x * 256 + threadIdx.x;  // 512*512
  int n = idx >> 9, k = idx & 511;
  Wt[idx] = f2bf(W[(k << 9) + n]);
}

__global__ void pack_zgr_k(const float* __restrict__ dgmW, unsigned short* __restrict__ Wt) {
  long idx = (long)blockIdx.x * 256 + threadIdx.x;  // 3*1536*1024
  int l = (int)(idx / (1536 * 1024));
  int rest = (int)(idx - (long)l * (1536 * 1024));
  int n = rest >> 10, k = rest & 1023;
  int g = n >> 9, nn = n & 511;
  const int xi0[3] = {0, 3, 6};
  const int xi1[3] = {2, 4, 8};
  const int si[3] = {1, 5, 7};
  float v;
  if (k < 512)
    v = dgmW[(((long)(l * 12 + xi0[g]) << 9) + k) * 512 + nn] +
        dgmW[(((long)(l * 12 + xi1[g]) << 9) + k) * 512 + nn];
  else
    v = dgmW[(((long)(l * 12 + si[g]) << 9) + (k - 512)) * 512 + nn];
  Wt[idx] = f2bf(v);
}

__global__ void pack_h_k(const float* __restrict__ dgmW, unsigned short* __restrict__ Wt) {
  long idx = (long)blockIdx.x * 256 + threadIdx.x;  // 3*512*1024
  int l = (int)(idx / (512 * 1024));
  int rest = (int)(idx - (long)l * (512 * 1024));
  int n = rest >> 10, k = rest & 1023;
  float v;
  if (k < 512)
    v = dgmW[(((long)(l * 12 + 9) << 9) + k) * 512 + n] +
        dgmW[(((long)(l * 12 + 11) << 9) + k) * 512 + n];
  else
    v = dgmW[(((long)(l * 12 + 10) << 9) + (k - 512)) * 512 + n];
  Wt[idx] = f2bf(v);
}

__global__ void pack_bias_k(const float* __restrict__ dgmb, float* __restrict__ bzgr,
                            float* __restrict__ bh) {
  int idx = blockIdx.x * 256 + threadIdx.x;  // 3*2048
  if (idx >= 3 * 2048) return;
  int l = idx >> 11, n = idx & 2047;
  const float* bl = dgmb + l * 12 * 512;
  if (n < 1536) {
    int g = n >> 9, nn = n & 511;
    bzgr[l * 1536 + n] =
        bl[(g * 3 + 0) * 512 + nn] + bl[(g * 3 + 1) * 512 + nn] + bl[(g * 3 + 2) * 512 + nn];
  } else {
    int nn = n - 1536;
    bh[l * 512 + nn] = bl[9 * 512 + nn] + bl[10 * 512 + nn] + bl[11 * 512 + nn];
  }
}

// ---------- front input layer ----------
__global__ void front0_k(const float* __restrict__ X, const float* __restrict__ t,
                         const float* __restrict__ Win, const float* __restrict__ bin,
                         unsigned short* __restrict__ x0, long row0) {
  long idx = (long)blockIdx.x * 256 + threadIdx.x;  // rows*512
  long r = idx >> 9;
  int c = (int)(idx & 511);
  long gr = row0 + r;
  float a = X[gr * 2] * Win[c] + X[gr * 2 + 1] * Win[512 + c] + t[gr] * Win[1024 + c] + bin[c];
  x0[idx] = f2bf(tanhf(a));
}

// ---------- output head ----------
__global__ void head_k(const unsigned short* __restrict__ S, const float* __restrict__ Wout,
                       const float* __restrict__ bout, float* __restrict__ out, long row0) {
  const int lane = threadIdx.x & 63, wid = threadIdx.x >> 6;
  const long r = (long)blockIdx.x * 4 + wid;
  bf16x8 sv = *(const bf16x8*)&S[r * 512 + lane * 8];
  float sum = 0.f;
#pragma unroll
  for (int i = 0; i < 8; ++i) sum += bf2f((unsigned short)sv[i]) * Wout[lane * 8 + i];
#pragma unroll
  for (int off = 32; off > 0; off >>= 1) sum += __shfl_down(sum, off);
  if (lane == 0) out[row0 + r] = sum + bout[0];
}

// ---------- persistent-M 256x256 8-phase GEMM ----------
// C[row][col] = act( sum_k A[row][k]*Wt[col][k] + bias[col] )
// Jobs = (mtile, col) flattened COL-FASTEST (jj = mt*NCOL + col) so
// consecutive jobs share the A-panel (L2-local with XCD-contiguous bsw).
// Each block runs jpb jobs; the 8-phase staging pipeline flows continuously
// across job boundaries (fill paid once per block, not per K=KT*64).
// LDS: [2 parity][A(2 ks)|B(2 ks)][256][32] bf16 = 128 KiB.
// vmcnt discipline (corrected from R2): vmcnt(5) at end of ph2 and ph4,
// vmcnt(0) only in the last 3 tiles of the block.
template <int EPI, int KT, int LOGKT, int NCOL>
__global__ __launch_bounds__(512, 2) void gemmP_k(
    const unsigned short* __restrict__ a0, const unsigned short* __restrict__ a1,
    const unsigned short* __restrict__ wt, const float* __restrict__ bias,
    unsigned short* __restrict__ o0, unsigned short* __restrict__ o1,
    unsigned short* __restrict__ o2, const unsigned short* __restrict__ e0,
    const unsigned short* __restrict__ e1, int njobs, int jpb) {
  constexpr int K = KT * 64;
  extern __shared__ unsigned short lds[];
  const int tid = threadIdx.x;
  const int lane = tid & 63, wid = tid >> 6;
  const int wm = wid >> 2, wn = wid & 3;
  const int lr = lane & 15, kk = lane >> 4;

  // XCD-contiguous bijective block swizzle (m204) on [0,G)
  const int G = gridDim.x;
  const int q = G >> 3, rr = G & 7;
  const int xcd = (int)blockIdx.x & 7, lo = (int)blockIdx.x >> 3;
  const int bsw = ((xcd < rr) ? xcd * (q + 1) : rr * (q + 1) + (xcd - rr) * q) + lo;
  const int j0 = bsw * jpb;
  if (j0 >= njobs) return;
  const int nj = min(jpb, njobs - j0);
  const int nseq = nj << LOGKT;

  // lane-constant address pieces.
  // LDS read: row = (warp base + m*16 + lr); swizzle granule
  // gp = kk ^ ((row>>1)&3) == kk ^ ((lr>>1)&3)  (warp/m parts are ≡0 mod 4).
  const int gp8 = ((kk ^ ((lr >> 1) & 3)) << 3);
  const int a_rd = (wm * 128 + lr) * 32 + gp8;         // + mh*2048 + m*512 + ks*8192 + cbo
  const int b_rd = 16384 + (wn * 64 + lr) * 32 + gp8;  // + n*512 + ks*8192 + cbo
  // stage lane pieces: c = tid (+512); r = c>>2; gl = (c&3)^((r>>1)&3)
  const int r0 = tid >> 2, gl0 = (tid & 3) ^ ((r0 >> 1) & 3);
  const int c1 = tid + 512, r1 = c1 >> 2, gl1 = (c1 & 3) ^ ((r1 >> 1) & 3);
  const int aL0 = r0 * 512 + gl0 * 8, aL1 = r1 * 512 + gl1 * 8;
  const size_t bL0 = (size_t)r0 * K + gl0 * 8, bL1 = (size_t)r1 * K + gl1 * 8;
  const int dL0 = tid * 8, dL1 = (tid + 512) * 8;

  f32x4 acc[8][4] = {};
  bf16x8 af[4], bf[4];

  auto stA = [&](int s2, int ks) {
    if (s2 >= nseq) return;
    const int jj = j0 + (s2 >> LOGKT);
    const int mt = jj / NCOL;
    const int kt2 = s2 & (KT - 1);
    const unsigned short* src = (KT == 16 && (kt2 & 8)) ? a1 : a0;
    const long pb = (long)mt * 131072 + (kt2 & 7) * 64 + ks * 32;
    const int d = ((s2 & 1) << 15) + ks * 8192;
    __builtin_amdgcn_global_load_lds(
        (const __attribute__((address_space(1))) void*)(src + pb + aL0),
        (__attribute__((address_space(3))) void*)(lds + d + dL0), 16, 0, 0);
    __builtin_amdgcn_global_load_lds(
        (const __attribute__((address_space(1))) void*)(src + pb + aL1),
        (__attribute__((address_space(3))) void*)(lds + d + dL1), 16, 0, 0);
  };
  auto stB = [&](int s2, int ks) {
    if (s2 >= nseq) return;
    const int jj = j0 + (s2 >> LOGKT);
    const int col = jj % NCOL;
    const int kt2 = s2 & (KT - 1);
    const size_t pb = (size_t)col * (256 * K) + kt2 * 64 + ks * 32;
    const int d = ((s2 & 1) << 15) + 16384 + ks * 8192;
    __builtin_amdgcn_global_load_lds(
        (const __attribute__((address_space(1))) void*)(wt + pb + bL0),
        (__attribute__((address_space(3))) void*)(lds + d + dL0), 16, 0, 0);
    __builtin_amdgcn_global_load_lds(
        (const __attribute__((address_space(1))) void*)(wt + pb + bL1),
        (__attribute__((address_space(3))) void*)(lds + d + dL1), 16, 0, 0);
  };
  auto ldA = [&](int cbo, int mh, int ks) {
#pragma unroll
    for (int m = 0; m < 4; ++m)
      af[m] = *(const bf16x8*)(lds + cbo + ks * 8192 + a_rd + mh * 2048 + m * 512);
  };
  auto ldB = [&](int cbo, int ks) {
#pragma unroll
    for (int n = 0; n < 4; ++n)
      bf[n] = *(const bf16x8*)(lds + cbo + ks * 8192 + b_rd + n * 512);
  };
  auto mmq = [&](int mh) {
    __builtin_amdgcn_s_setprio(1);
#pragma unroll
    for (int m = 0; m < 4; ++m)
#pragma unroll
      for (int n = 0; n < 4; ++n)
        acc[mh * 4 + m][n] =
            __builtin_amdgcn_mfma_f32_16x16x32_bf16(af[m], bf[n], acc[mh * 4 + m][n], 0, 0, 0);
    __builtin_amdgcn_s_setprio(0);
  };

  // prologue: tile0 complete + 3 units of tile1
  stB(0, 0);
  stA(0, 0);
  stB(0, 1);
  stA(0, 1);
  stB(1, 0);
  stA(1, 0);
  stB(1, 1);
  asm volatile("s_waitcnt vmcnt(5)" ::: "memory");
  __builtin_amdgcn_s_barrier();

  for (int s = 0; s < nseq; ++s) {
    const int cbo = (s & 1) << 15;
    const bool deep = (s + 4 <= nseq);
    // ph1: (m0-3, ks0); stage (s+1).Aks1
    ldB(cbo, 0);
    ldA(cbo, 0, 0);
    stA(s + 1, 1);
    __builtin_amdgcn_s_barrier();
    mmq(0);
    __builtin_amdgcn_s_barrier();
    // ph2: (m4-7, ks0); stage (s+2).Bks0
    ldA(cbo, 1, 0);
    stB(s + 2, 0);
    __builtin_amdgcn_s_barrier();
    mmq(1);
    if (deep)
      asm volatile("s_waitcnt vmcnt(5)" ::: "memory");
    else
      asm volatile("s_waitcnt vmcnt(0)" ::: "memory");
    __builtin_amdgcn_s_barrier();
    // ph3: (m0-3, ks1); stage (s+2).Aks0
    ldB(cbo, 1);
    ldA(cbo, 0, 1);
    stA(s + 2, 0);
    __builtin_amdgcn_s_barrier();
    mmq(0);
    __builtin_amdgcn_s_barrier();
    // ph4: (m4-7, ks1); stage (s+2).Bks1
    ldA(cbo, 1, 1);
    stB(s + 2, 1);
    __builtin_amdgcn_s_barrier();
    mmq(1);
    if (deep)
      asm volatile("s_waitcnt vmcnt(5)" ::: "memory");
    else
      asm volatile("s_waitcnt vmcnt(0)" ::: "memory");
    __builtin_amdgcn_s_barrier();

    if ((s & (KT - 1)) == (KT - 1)) {
      // epilogue for finished job
      const int jj = j0 + (s >> LOGKT);
      const long brow = (long)(jj / NCOL) * 256;
      const int bcol = (jj % NCOL) * 256;
#pragma unroll
      for (int m = 0; m < 8; ++m) {
#pragma unroll
        for (int n = 0; n < 4; ++n) {
          const int col = bcol + wn * 64 + n * 16 + lr;
          const float bs = bias[col];
#pragma unroll
          for (int j = 0; j < 4; ++j) {
            const long row = brow + wm * 128 + m * 16 + kk * 4 + j;
            float v = acc[m][n][j] + bs;
            if constexpr (EPI == 0) {
              o0[row * 512 + col] = f2bf(tanhf(v));
            } else if constexpr (EPI == 1) {
              unsigned short b = f2bf(v);
              o0[row * 512 + col] = b;
              o1[row * 512 + col] = b;
            } else if constexpr (EPI == 2) {
              const int g = col >> 9;
              const int nn = col & 511;
              const float sgv = sigm(v);
              if (g == 0) {
                o0[row * 512 + nn] = f2bf(sgv * bf2f(e0[row * 512 + nn]));  // Z*S
              } else if (g == 1) {
                o1[row * 512 + nn] = f2bf(1.0f - sgv);  // 1-G
              } else {
                o2[row * 512 + nn] = f2bf(sgv * bf2f(e0[row * 512 + nn]));  // S*R
              }
            } else {
              const float h = tanhf(v);
              const float omg = bf2f(e0[row * 512 + col]);
              const float zs = bf2f(e1[row * 512 + col]);
              o0[row * 512 + col] = f2bf(omg * h + zs);  // S_new
            }
            acc[m][n][j] = 0.0f;
          }
        }
      }
    }
  }
}

}  // namespace

extern "C" void kernel_launch(void* const* d_in, const int* in_sizes, int n_in,
                              void* d_out, int out_size, void* d_ws, size_t ws_size,
                              hipStream_t stream) {
  const float* X = (const float*)d_in[0];
  const float* t = (const float*)d_in[1];
  const float* W_in = (const float*)d_in[2];
  const float* b_in = (const float*)d_in[3];
  const float* W_h1 = (const float*)d_in[4];
  const float* b_h1 = (const float*)d_in[5];
  const float* W_hd = (const float*)d_in[6];
  const float* b_hd = (const float*)d_in[7];
  const float* dgm_W = (const float*)d_in[8];
  const float* dgm_b = (const float*)d_in[9];
  const float* W_out = (const float*)d_in[10];
  const float* b_out = (const float*)d_in[11];
  float* out = (float*)d_out;
  char* ws = (char*)d_ws;

  // allow 128 KiB dynamic LDS (host-side, capture-safe)
  (void)hipFuncSetAttribute((const void*)&gemmP_k<0, 8, 3, 2>,
                            hipFuncAttributeMaxDynamicSharedMemorySize, 131072);
  (void)hipFuncSetAttribute((const void*)&gemmP_k<1, 8, 3, 2>,
                            hipFuncAttributeMaxDynamicSharedMemorySize, 131072);
  (void)hipFuncSetAttribute((const void*)&gemmP_k<2, 16, 4, 6>,
                            hipFuncAttributeMaxDynamicSharedMemorySize, 131072);
  (void)hipFuncSetAttribute((const void*)&gemmP_k<3, 16, 4, 2>,
                            hipFuncAttributeMaxDynamicSharedMemorySize, 131072);

  size_t off = 0;
  auto alloc = [&](size_t bytes) {
    size_t o = off;
    off = (off + bytes + 255) & ~(size_t)255;
    return o;
  };
  size_t o_wth1 = alloc((size_t)512 * 512 * 2);
  size_t o_wthd = alloc((size_t)512 * 512 * 2);
  size_t o_wtzgr = alloc((size_t)3 * 1536 * 1024 * 2);
  size_t o_wth = alloc((size_t)3 * 512 * 1024 * 2);
  size_t o_bzgr = alloc((size_t)3 * 1536 * 4);
  size_t o_bh = alloc((size_t)3 * 512 * 4);
  size_t actoff = off;

  unsigned short* wth1 = (unsigned short*)(ws + o_wth1);
  unsigned short* wthd = (unsigned short*)(ws + o_wthd);
  unsigned short* wtzgr = (unsigned short*)(ws + o_wtzgr);
  unsigned short* wth = (unsigned short*)(ws + o_wth);
  float* bzgr = (float*)(ws + o_bzgr);
  float* bh = (float*)(ws + o_bh);

  // chunk batch: 5 bf16 [R,512] activation buffers in remaining ws; R % 256 == 0
  size_t avail = ws_size > actoff ? ws_size - actoff : 0;
  int nch = 1;
  while (nch < 256 && (size_t)(B_ROWS / nch) * 512 * 2 * 5 > avail) nch <<= 1;
  const int R = B_ROWS / nch;
  unsigned short* xb = (unsigned short*)(ws + actoff);
  unsigned short* Sb = xb + (size_t)R * 512;
  unsigned short* ZSb = Sb + (size_t)R * 512;
  unsigned short* OGb = ZSb + (size_t)R * 512;
  unsigned short* SRb = OGb + (size_t)R * 512;

  pack_t_k<<<1024, 256, 0, stream>>>(W_h1, wth1);
  pack_t_k<<<1024, 256, 0, stream>>>(W_hd, wthd);
  pack_zgr_k<<<18432, 256, 0, stream>>>(dgm_W, wtzgr);
  pack_h_k<<<6144, 256, 0, stream>>>(dgm_W, wth);
  pack_bias_k<<<24, 256, 0, stream>>>(dgm_b, bzgr, bh);

  const int MT = R / 256;
  auto cfg = [](int njobs, int& jpb, int& G) {
    jpb = (njobs + 255) / 256;
    G = (njobs + jpb - 1) / jpb;
  };
  int nj2 = 2 * MT, jpb2, G2;
  cfg(nj2, jpb2, G2);
  int nj6 = 6 * MT, jpb6, G6;
  cfg(nj6, jpb6, G6);

  for (int c = 0; c < nch; ++c) {
    long row0 = (long)c * R;
    // x0 = tanh(inp@W_in + b_in)  -> ZSb (scratch)
    front0_k<<<R * 2, 256, 0, stream>>>(X, t, W_in, b_in, ZSb, row0);
    // x1 = tanh(x0@W_h1 + b_h1)   -> OGb (scratch)
    gemmP_k<0, 8, 3, 2><<<G2, 512, 131072, stream>>>(ZSb, ZSb, wth1, b_h1, OGb, nullptr,
                                                     nullptr, nullptr, nullptr, nj2, jpb2);
    // x = x1@W_hd + b_hd          -> xb and Sb
    gemmP_k<1, 8, 3, 2><<<G2, 512, 131072, stream>>>(OGb, OGb, wthd, b_hd, xb, Sb, nullptr,
                                                     nullptr, nullptr, nj2, jpb2);
    for (int l = 0; l < 3; ++l) {
      // gates: [x|S] @ Wzgr -> Z*S, 1-G, S*R
      gemmP_k<2, 16, 4, 6><<<G6, 512, 131072, stream>>>(
          xb, Sb, wtzgr + (size_t)l * 1536 * 1024, bzgr + l * 1536, ZSb, OGb, SRb, Sb,
          nullptr, nj6, jpb6);
      // H + S update: [x|S*R] @ Wh ; S = (1-G)*tanh + Z*S
      gemmP_k<3, 16, 4, 2><<<G2, 512, 131072, stream>>>(
          xb, SRb, wth + (size_t)l * 512 * 1024, bh + l * 512, Sb, nullptr, nullptr, OGb,
          ZSb, nj2, jpb2);
    }
    head_k<<<R / 4, 256, 0, stream>>>(Sb, W_out, b_out, out, row0);
  }
}